// Round 5
// baseline (243.696 us; speedup 1.0000x reference)
//
#include <hip/hip_runtime.h>
#include <math.h>

// Problem constants
#define M_ 16
#define N_ 4096
#define D_ 128
#define P_ 8192
#define H_ 32

// Projection tiling
#define NIC 32
#define ICH (N_/NIC)
#define NCB 16            // 256-column blocks, 1 col/thread

// Attention chunking
#define CHUNK 128
#define NCH (P_/CHUNK)    // 64 cache chunks
#define NCH1 (NCH+1)      // +1 for the 16 appended rows

// Workspace layout (float offsets)
#define QKV_SZ    (3*H_*M_*D_)
#define PART_OFF  (QKV_SZ)
#define OPART_OFF (QKV_SZ)
#define OPART_SZ  (H_*NCH1*M_*D_)
#define ML_OFF    (OPART_OFF + OPART_SZ)

// ---------------------------------------------------------------------------
// Kernel 1: partial QKV projection. grid (NCB, NIC, 3), block 256.
// 1 output column x 16 rows per thread over a 128-long i-chunk.
// ---------------------------------------------------------------------------
__global__ __launch_bounds__(256) void k_proj(const float* __restrict__ X,
                                              const float* __restrict__ Wq,
                                              const float* __restrict__ Wk,
                                              const float* __restrict__ Wv,
                                              float* __restrict__ part) {
  const int mat = blockIdx.z;
  const float* __restrict__ W = (mat == 0) ? Wq : ((mat == 1) ? Wk : Wv);
  const int cb = blockIdx.x, ic = blockIdx.y;
  const int t = threadIdx.x;
  const int j0 = cb * 256 + t;
  const int i0 = ic * ICH;

  __shared__ __align__(16) float XT[ICH][20];

  {
    const int i_l = t & 127, mh = t >> 7;
#pragma unroll
    for (int r = 0; r < 8; ++r)
      XT[i_l][mh * 8 + r] = X[(size_t)(mh * 8 + r) * N_ + i0 + i_l];
  }
  __syncthreads();

  float acc[16];
#pragma unroll
  for (int m = 0; m < 16; ++m) acc[m] = 0.f;

#pragma unroll 8
  for (int i = 0; i < ICH; ++i) {
    const float wv = W[(size_t)(i0 + i) * N_ + j0];
    float xr[16];
    {
      float4 xv;
      xv = *reinterpret_cast<const float4*>(&XT[i][0]);
      xr[0] = xv.x; xr[1] = xv.y; xr[2] = xv.z; xr[3] = xv.w;
      xv = *reinterpret_cast<const float4*>(&XT[i][4]);
      xr[4] = xv.x; xr[5] = xv.y; xr[6] = xv.z; xr[7] = xv.w;
      xv = *reinterpret_cast<const float4*>(&XT[i][8]);
      xr[8] = xv.x; xr[9] = xv.y; xr[10] = xv.z; xr[11] = xv.w;
      xv = *reinterpret_cast<const float4*>(&XT[i][12]);
      xr[12] = xv.x; xr[13] = xv.y; xr[14] = xv.z; xr[15] = xv.w;
    }
#pragma unroll
    for (int m = 0; m < 16; ++m) acc[m] = fmaf(xr[m], wv, acc[m]);
  }

#pragma unroll
  for (int m = 0; m < 16; ++m)
    part[(size_t)((mat * NIC + ic) * M_ + m) * N_ + j0] = acc[m];
}

// ---------------------------------------------------------------------------
// Kernel 2: reduce partials, RMS-norm q/k, relayout. (unchanged)
// ---------------------------------------------------------------------------
__global__ __launch_bounds__(256) void k_reduce(const float* __restrict__ part,
                                                float* __restrict__ qkv) {
  const int mat = blockIdx.z, m = blockIdx.y, nc = blockIdx.x;
  const int t = threadIdx.x;
  const int n = nc * 256 + t;

  float s = 0.f;
#pragma unroll
  for (int ic = 0; ic < NIC; ++ic)
    s += part[(size_t)((mat * NIC + ic) * M_ + m) * N_ + n];

  float ss = s * s;
#pragma unroll
  for (int off = 1; off < 64; off <<= 1) ss += __shfl_xor(ss, off);
  __shared__ float wsum[4];
  const int wave = t >> 6, lane = t & 63;
  if (lane == 0) wsum[wave] = ss;
  __syncthreads();
  const int half = t >> 7;
  const float tot = wsum[half * 2] + wsum[half * 2 + 1];
  const float scale = (mat < 2) ? rsqrtf(tot * (1.0f / 128.0f)) : 1.0f;

  const int h = n >> 7, d = n & 127;
  qkv[(size_t)((mat * H_ + h) * M_ + m) * D_ + d] = s * scale;
}

// ---------------------------------------------------------------------------
// Kernel 3: barrier-free streaming attention partials. grid (NCH1, H_),
// block 256 = 4 independent waves. Wave w owns output rows m0=4w..4w+3 and
// processes ALL rows of the block's 128-row chunk: K/V stream global->regs
// (coalesced), q from LDS (broadcast), weights exchanged through a
// wave-private LDS strip, online softmax in registers. ONE barrier total
// (after the q stage); latency hidden by ILP x TLP, not pipelining.
// ---------------------------------------------------------------------------
__global__ __launch_bounds__(256, 4) void k_attn(const float* __restrict__ cacheK,
                                                 const float* __restrict__ cacheV,
                                                 const float* __restrict__ qkv,
                                                 float* __restrict__ opart,
                                                 float* __restrict__ ml) {
  const int c = blockIdx.x, h = blockIdx.y;
  const int t = threadIdx.x;
  const int wave = t >> 6, lane = t & 63;
  const int valid = (c < NCH) ? CHUNK : M_;
  const int nsub = (valid + 31) >> 5;  // 4 full subtiles, or 1 for the tail
  const float* __restrict__ Ksrc = (c < NCH)
      ? (cacheK + ((size_t)h * P_ + (size_t)c * CHUNK) * D_)
      : (qkv + (size_t)((1 * H_ + h) * M_) * D_);
  const float* __restrict__ Vsrc = (c < NCH)
      ? (cacheV + ((size_t)h * P_ + (size_t)c * CHUNK) * D_)
      : (qkv + (size_t)((2 * H_ + h) * M_) * D_);

  __shared__ __align__(16) float qs[M_ * D_];   // 8 KB, broadcast reads only
  __shared__ float wx[4][2][32][2];             // 2 KB wave-private weight strips

  // stage q (one barrier, the only one in the kernel)
  {
    const float4* src = reinterpret_cast<const float4*>(qkv + (size_t)(h * M_) * D_);
    float4* dst = reinterpret_cast<float4*>(qs);
    dst[t] = src[t];
    dst[t + 256] = src[t + 256];
  }
  __syncthreads();

  const int pg = lane >> 3, dq = lane & 7;  // scores: 8 rows x 8 d-groups
  const int m0 = wave * 4;
  const int dl = lane * 2;                  // PV: d-pair per lane

  float mrun[4] = {-3.0e38f, -3.0e38f, -3.0e38f, -3.0e38f};
  float lrun[4] = {0.f, 0.f, 0.f, 0.f};
  float2 o[4];
#pragma unroll
  for (int mi = 0; mi < 4; ++mi) o[mi] = make_float2(0.f, 0.f);

#pragma unroll 1
  for (int sub = 0; sub < nsub; ++sub) {
    const int rb = sub * 32 + pg;

    // ---- scores: a[mi][pi] = q[m0+mi] . K[rb+8pi], d-split over dq ----
    float a[4][4];
#pragma unroll
    for (int mi = 0; mi < 4; ++mi)
#pragma unroll
      for (int pi = 0; pi < 4; ++pi) a[mi][pi] = 0.f;

#pragma unroll
    for (int dd = 0; dd < 4; ++dd) {
      float4 kk[4];
#pragma unroll
      for (int pi = 0; pi < 4; ++pi) {
        int gp = rb + 8 * pi; gp = (gp < valid) ? gp : (valid - 1);
        kk[pi] = *reinterpret_cast<const float4*>(Ksrc + (size_t)gp * D_ + dd * 32 + dq * 4);
      }
      float4 qq[4];
#pragma unroll
      for (int mi = 0; mi < 4; ++mi)
        qq[mi] = *reinterpret_cast<const float4*>(&qs[(m0 + mi) * D_ + dd * 32 + dq * 4]);
#pragma unroll
      for (int mi = 0; mi < 4; ++mi)
#pragma unroll
        for (int pi = 0; pi < 4; ++pi) {
          a[mi][pi] = fmaf(qq[mi].x, kk[pi].x, a[mi][pi]);
          a[mi][pi] = fmaf(qq[mi].y, kk[pi].y, a[mi][pi]);
          a[mi][pi] = fmaf(qq[mi].z, kk[pi].z, a[mi][pi]);
          a[mi][pi] = fmaf(qq[mi].w, kk[pi].w, a[mi][pi]);
        }
    }
    // reduce d-split over dq lanes (bits 0..2)
#pragma unroll
    for (int off = 1; off < 8; off <<= 1)
#pragma unroll
      for (int mi = 0; mi < 4; ++mi)
#pragma unroll
        for (int pi = 0; pi < 4; ++pi)
          a[mi][pi] += __shfl_xor(a[mi][pi], off);

    // mask invalid rows (tail chunk)
#pragma unroll
    for (int pi = 0; pi < 4; ++pi)
      if (rb + 8 * pi >= valid) {
        a[0][pi] = -3.0e38f; a[1][pi] = -3.0e38f;
        a[2][pi] = -3.0e38f; a[3][pi] = -3.0e38f;
      }

    // online softmax per mi (row-max over pi in-lane, pg via shuffles)
    float w[4][4];
#pragma unroll
    for (int mi = 0; mi < 4; ++mi) {
      float tmax = fmaxf(fmaxf(a[mi][0], a[mi][1]), fmaxf(a[mi][2], a[mi][3]));
      tmax = fmaxf(tmax, __shfl_xor(tmax, 8));
      tmax = fmaxf(tmax, __shfl_xor(tmax, 16));
      tmax = fmaxf(tmax, __shfl_xor(tmax, 32));
      const float mnew = fmaxf(mrun[mi], tmax);
      const float fc = __expf(mrun[mi] - mnew);
      mrun[mi] = mnew;
      float rs = 0.f;
#pragma unroll
      for (int pi = 0; pi < 4; ++pi) {
        w[mi][pi] = __expf(a[mi][pi] - mnew);
        rs += w[mi][pi];
      }
      rs += __shfl_xor(rs, 8);
      rs += __shfl_xor(rs, 16);
      rs += __shfl_xor(rs, 32);
      lrun[mi] = lrun[mi] * fc + rs;
      o[mi].x *= fc;
      o[mi].y *= fc;
    }

    // publish weights to the wave-private strip: lane (pg, dq<4) owns row
    // p = pg + 8*dq; select w[.][dq] via static-index ternaries (no scratch).
    if (dq < 4) {
      const int p = pg + 8 * dq;
      const float s0 = (dq == 0) ? w[0][0] : (dq == 1) ? w[0][1] : (dq == 2) ? w[0][2] : w[0][3];
      const float s1 = (dq == 0) ? w[1][0] : (dq == 1) ? w[1][1] : (dq == 2) ? w[1][2] : w[1][3];
      const float s2 = (dq == 0) ? w[2][0] : (dq == 1) ? w[2][1] : (dq == 2) ? w[2][2] : w[2][3];
      const float s3 = (dq == 0) ? w[3][0] : (dq == 1) ? w[3][1] : (dq == 2) ? w[3][2] : w[3][3];
      *reinterpret_cast<float2*>(&wx[wave][0][p][0]) = make_float2(s0, s1);
      *reinterpret_cast<float2*>(&wx[wave][1][p][0]) = make_float2(s2, s3);
    }
    // wave-internal LDS ordering: in-order per wave; compiler keeps alias order.

    // ---- PV: o[mi] (d = dl, dl+1) over the 32 rows, V streamed per row ----
#pragma unroll
    for (int p8 = 0; p8 < 4; ++p8) {
      float2 vv[8];
#pragma unroll
      for (int j = 0; j < 8; ++j) {
        int gp = sub * 32 + p8 * 8 + j; gp = (gp < valid) ? gp : (valid - 1);
        vv[j] = *reinterpret_cast<const float2*>(Vsrc + (size_t)gp * D_ + dl);
      }
#pragma unroll
      for (int j = 0; j < 8; ++j) {
        const float2 wa = *reinterpret_cast<const float2*>(&wx[wave][0][p8 * 8 + j][0]);
        const float2 wb = *reinterpret_cast<const float2*>(&wx[wave][1][p8 * 8 + j][0]);
        o[0].x = fmaf(wa.x, vv[j].x, o[0].x); o[0].y = fmaf(wa.x, vv[j].y, o[0].y);
        o[1].x = fmaf(wa.y, vv[j].x, o[1].x); o[1].y = fmaf(wa.y, vv[j].y, o[1].y);
        o[2].x = fmaf(wb.x, vv[j].x, o[2].x); o[2].y = fmaf(wb.x, vv[j].y, o[2].y);
        o[3].x = fmaf(wb.y, vv[j].x, o[3].x); o[3].y = fmaf(wb.y, vv[j].y, o[3].y);
      }
    }
  }

  // ---- write partials: wave owns rows m0..m0+3 fully ----
  const size_t base = (size_t)((h * NCH1 + c) * M_) * D_;
#pragma unroll
  for (int mi = 0; mi < 4; ++mi)
    *reinterpret_cast<float2*>(opart + base + (size_t)(m0 + mi) * D_ + dl) = o[mi];
  if (lane == 0) {
    const size_t mb = ((size_t)(h * NCH1 + c) * M_ + m0) * 2;
    ml[mb + 0] = mrun[0]; ml[mb + 1] = lrun[0];
    ml[mb + 2] = mrun[1]; ml[mb + 3] = lrun[1];
    ml[mb + 4] = mrun[2]; ml[mb + 5] = lrun[2];
    ml[mb + 6] = mrun[3]; ml[mb + 7] = lrun[3];
  }
}

// ---------------------------------------------------------------------------
// Kernel 4: combine 65 chunk partials per (h, m). grid (M_, H_), block 128.
// 4-way split accumulators for load ILP.
// ---------------------------------------------------------------------------
__global__ __launch_bounds__(128) void k_comb(const float* __restrict__ opart,
                                              const float* __restrict__ ml,
                                              float* __restrict__ out) {
  const int m = blockIdx.x, h = blockIdx.y, t = threadIdx.x;
  __shared__ float Ms[NCH1], Ls[NCH1];
  if (t < NCH1) {
    Ms[t] = ml[((size_t)(h * NCH1 + t) * M_ + m) * 2 + 0];
    Ls[t] = ml[((size_t)(h * NCH1 + t) * M_ + m) * 2 + 1];
  }
  __syncthreads();
  float gM = -3.0e38f;
#pragma unroll
  for (int c2 = 0; c2 < NCH1; ++c2) gM = fmaxf(gM, Ms[c2]);

  const float* __restrict__ ob = opart + (size_t)h * NCH1 * M_ * D_ + (size_t)m * D_ + t;
  float T = 0.f, o0 = 0.f, o1 = 0.f, o2 = 0.f, o3 = 0.f;
#pragma unroll 4
  for (int c2 = 0; c2 < NCH1 - 1; c2 += 4) {
    const float f0 = __expf(Ms[c2 + 0] - gM);
    const float f1 = __expf(Ms[c2 + 1] - gM);
    const float f2 = __expf(Ms[c2 + 2] - gM);
    const float f3 = __expf(Ms[c2 + 3] - gM);
    T = fmaf(Ls[c2 + 0], f0, T); T = fmaf(Ls[c2 + 1], f1, T);
    T = fmaf(Ls[c2 + 2], f2, T); T = fmaf(Ls[c2 + 3], f3, T);
    o0 = fmaf(ob[(size_t)(c2 + 0) * M_ * D_], f0, o0);
    o1 = fmaf(ob[(size_t)(c2 + 1) * M_ * D_], f1, o1);
    o2 = fmaf(ob[(size_t)(c2 + 2) * M_ * D_], f2, o2);
    o3 = fmaf(ob[(size_t)(c2 + 3) * M_ * D_], f3, o3);
  }
  {
    const int c2 = NCH1 - 1;
    const float f = __expf(Ms[c2] - gM);
    T = fmaf(Ls[c2], f, T);
    o0 = fmaf(ob[(size_t)c2 * M_ * D_], f, o0);
  }
  out[(size_t)m * N_ + h * D_ + t] = (o0 + o1 + o2 + o3) / T;
}

// ---------------------------------------------------------------------------
extern "C" void kernel_launch(void* const* d_in, const int* in_sizes, int n_in,
                              void* d_out, int out_size, void* d_ws, size_t ws_size,
                              hipStream_t stream) {
  const float* X  = (const float*)d_in[0];
  const float* Wq = (const float*)d_in[1];
  const float* Wk = (const float*)d_in[2];
  const float* Wv = (const float*)d_in[3];
  const float* cK = (const float*)d_in[4];
  const float* cV = (const float*)d_in[5];
  float* ws    = (float*)d_ws;
  float* qkv   = ws;
  float* part  = ws + PART_OFF;
  float* opart = ws + OPART_OFF;
  float* mlbuf = ws + ML_OFF;
  float* out   = (float*)d_out;

  hipLaunchKernelGGL(k_proj,   dim3(NCB, NIC, 3), dim3(256), 0, stream, X, Wq, Wk, Wv, part);
  hipLaunchKernelGGL(k_reduce, dim3(16, M_, 3),   dim3(256), 0, stream, part, qkv);
  hipLaunchKernelGGL(k_attn,   dim3(NCH1, H_),    dim3(256), 0, stream, cK, cV, qkv, opart, mlbuf);
  hipLaunchKernelGGL(k_comb,   dim3(M_, H_),      dim3(128), 0, stream, opart, mlbuf, out);
}

// Round 6
// 159.532 us; speedup vs baseline: 1.5276x; 1.5276x over previous
//
#include <hip/hip_runtime.h>
#include <math.h>

// Problem constants
#define M_ 16
#define N_ 4096
#define D_ 128
#define P_ 8192
#define H_ 32

// Projection tiling
#define NIC 32
#define ICH (N_/NIC)
#define NCB 16            // 256-column blocks, 1 col/thread

// Attention chunking
#define CHUNK 128
#define NCH (P_/CHUNK)    // 64 cache chunks
#define NCH1 (NCH+1)      // +1 for the 16 appended rows

// Workspace layout (float offsets)
#define QKV_SZ    (3*H_*M_*D_)
#define PART_OFF  (QKV_SZ)
#define OPART_OFF (QKV_SZ)
#define OPART_SZ  (H_*NCH1*M_*D_)
#define ML_OFF    (OPART_OFF + OPART_SZ)

// ---------------------------------------------------------------------------
// Kernel 1: partial QKV projection. grid (NCB, NIC, 3), block 256.
// 1 output column x 16 rows per thread over a 128-long i-chunk. (unchanged)
// ---------------------------------------------------------------------------
__global__ __launch_bounds__(256) void k_proj(const float* __restrict__ X,
                                              const float* __restrict__ Wq,
                                              const float* __restrict__ Wk,
                                              const float* __restrict__ Wv,
                                              float* __restrict__ part) {
  const int mat = blockIdx.z;
  const float* __restrict__ W = (mat == 0) ? Wq : ((mat == 1) ? Wk : Wv);
  const int cb = blockIdx.x, ic = blockIdx.y;
  const int t = threadIdx.x;
  const int j0 = cb * 256 + t;
  const int i0 = ic * ICH;

  __shared__ __align__(16) float XT[ICH][20];

  {
    const int i_l = t & 127, mh = t >> 7;
#pragma unroll
    for (int r = 0; r < 8; ++r)
      XT[i_l][mh * 8 + r] = X[(size_t)(mh * 8 + r) * N_ + i0 + i_l];
  }
  __syncthreads();

  float acc[16];
#pragma unroll
  for (int m = 0; m < 16; ++m) acc[m] = 0.f;

#pragma unroll 8
  for (int i = 0; i < ICH; ++i) {
    const float wv = W[(size_t)(i0 + i) * N_ + j0];
    float xr[16];
    {
      float4 xv;
      xv = *reinterpret_cast<const float4*>(&XT[i][0]);
      xr[0] = xv.x; xr[1] = xv.y; xr[2] = xv.z; xr[3] = xv.w;
      xv = *reinterpret_cast<const float4*>(&XT[i][4]);
      xr[4] = xv.x; xr[5] = xv.y; xr[6] = xv.z; xr[7] = xv.w;
      xv = *reinterpret_cast<const float4*>(&XT[i][8]);
      xr[8] = xv.x; xr[9] = xv.y; xr[10] = xv.z; xr[11] = xv.w;
      xv = *reinterpret_cast<const float4*>(&XT[i][12]);
      xr[12] = xv.x; xr[13] = xv.y; xr[14] = xv.z; xr[15] = xv.w;
    }
#pragma unroll
    for (int m = 0; m < 16; ++m) acc[m] = fmaf(xr[m], wv, acc[m]);
  }

#pragma unroll
  for (int m = 0; m < 16; ++m)
    part[(size_t)((mat * NIC + ic) * M_ + m) * N_ + j0] = acc[m];
}

// ---------------------------------------------------------------------------
// Kernel 2: reduce partials, RMS-norm q/k, relayout. (unchanged)
// ---------------------------------------------------------------------------
__global__ __launch_bounds__(256) void k_reduce(const float* __restrict__ part,
                                                float* __restrict__ qkv) {
  const int mat = blockIdx.z, m = blockIdx.y, nc = blockIdx.x;
  const int t = threadIdx.x;
  const int n = nc * 256 + t;

  float s = 0.f;
#pragma unroll
  for (int ic = 0; ic < NIC; ++ic)
    s += part[(size_t)((mat * NIC + ic) * M_ + m) * N_ + n];

  float ss = s * s;
#pragma unroll
  for (int off = 1; off < 64; off <<= 1) ss += __shfl_xor(ss, off);
  __shared__ float wsum[4];
  const int wave = t >> 6, lane = t & 63;
  if (lane == 0) wsum[wave] = ss;
  __syncthreads();
  const int half = t >> 7;
  const float tot = wsum[half * 2] + wsum[half * 2 + 1];
  const float scale = (mat < 2) ? rsqrtf(tot * (1.0f / 128.0f)) : 1.0f;

  const int h = n >> 7, d = n & 127;
  qkv[(size_t)((mat * H_ + h) * M_ + m) * D_ + d] = s * scale;
}

// ---------------------------------------------------------------------------
// Kernel 3: barrier-free streaming attention partials. grid (NCH1, H_),
// block 256 = 4 independent waves. IDENTICAL to round 5 except
// __launch_bounds__(256, 2): round 5's (256,4) clamped the allocator to the
// 64-VGPR occupancy step and spilled ~50 regs/thread to scratch
// (WRITE_SIZE 160MB, FETCH 344MB). Demand is ~110-130 VGPR; (256,2) caps at
// 256 so no spill; runtime occupancy still reaches 4 blocks/CU if <=128.
// ---------------------------------------------------------------------------
__global__ __launch_bounds__(256, 2) void k_attn(const float* __restrict__ cacheK,
                                                 const float* __restrict__ cacheV,
                                                 const float* __restrict__ qkv,
                                                 float* __restrict__ opart,
                                                 float* __restrict__ ml) {
  const int c = blockIdx.x, h = blockIdx.y;
  const int t = threadIdx.x;
  const int wave = t >> 6, lane = t & 63;
  const int valid = (c < NCH) ? CHUNK : M_;
  const int nsub = (valid + 31) >> 5;  // 4 full subtiles, or 1 for the tail
  const float* __restrict__ Ksrc = (c < NCH)
      ? (cacheK + ((size_t)h * P_ + (size_t)c * CHUNK) * D_)
      : (qkv + (size_t)((1 * H_ + h) * M_) * D_);
  const float* __restrict__ Vsrc = (c < NCH)
      ? (cacheV + ((size_t)h * P_ + (size_t)c * CHUNK) * D_)
      : (qkv + (size_t)((2 * H_ + h) * M_) * D_);

  __shared__ __align__(16) float qs[M_ * D_];   // 8 KB, broadcast reads only
  __shared__ float wx[4][2][32][2];             // 2 KB wave-private weight strips

  // stage q (one barrier, the only one in the kernel)
  {
    const float4* src = reinterpret_cast<const float4*>(qkv + (size_t)(h * M_) * D_);
    float4* dst = reinterpret_cast<float4*>(qs);
    dst[t] = src[t];
    dst[t + 256] = src[t + 256];
  }
  __syncthreads();

  const int pg = lane >> 3, dq = lane & 7;  // scores: 8 rows x 8 d-groups
  const int m0 = wave * 4;
  const int dl = lane * 2;                  // PV: d-pair per lane

  float mrun[4] = {-3.0e38f, -3.0e38f, -3.0e38f, -3.0e38f};
  float lrun[4] = {0.f, 0.f, 0.f, 0.f};
  float2 o[4];
#pragma unroll
  for (int mi = 0; mi < 4; ++mi) o[mi] = make_float2(0.f, 0.f);

#pragma unroll 1
  for (int sub = 0; sub < nsub; ++sub) {
    const int rb = sub * 32 + pg;

    // ---- scores: a[mi][pi] = q[m0+mi] . K[rb+8pi], d-split over dq ----
    float a[4][4];
#pragma unroll
    for (int mi = 0; mi < 4; ++mi)
#pragma unroll
      for (int pi = 0; pi < 4; ++pi) a[mi][pi] = 0.f;

#pragma unroll
    for (int dd = 0; dd < 4; ++dd) {
      float4 kk[4];
#pragma unroll
      for (int pi = 0; pi < 4; ++pi) {
        int gp = rb + 8 * pi; gp = (gp < valid) ? gp : (valid - 1);
        kk[pi] = *reinterpret_cast<const float4*>(Ksrc + (size_t)gp * D_ + dd * 32 + dq * 4);
      }
      float4 qq[4];
#pragma unroll
      for (int mi = 0; mi < 4; ++mi)
        qq[mi] = *reinterpret_cast<const float4*>(&qs[(m0 + mi) * D_ + dd * 32 + dq * 4]);
#pragma unroll
      for (int mi = 0; mi < 4; ++mi)
#pragma unroll
        for (int pi = 0; pi < 4; ++pi) {
          a[mi][pi] = fmaf(qq[mi].x, kk[pi].x, a[mi][pi]);
          a[mi][pi] = fmaf(qq[mi].y, kk[pi].y, a[mi][pi]);
          a[mi][pi] = fmaf(qq[mi].z, kk[pi].z, a[mi][pi]);
          a[mi][pi] = fmaf(qq[mi].w, kk[pi].w, a[mi][pi]);
        }
    }
    // reduce d-split over dq lanes (bits 0..2)
#pragma unroll
    for (int off = 1; off < 8; off <<= 1)
#pragma unroll
      for (int mi = 0; mi < 4; ++mi)
#pragma unroll
        for (int pi = 0; pi < 4; ++pi)
          a[mi][pi] += __shfl_xor(a[mi][pi], off);

    // mask invalid rows (tail chunk)
#pragma unroll
    for (int pi = 0; pi < 4; ++pi)
      if (rb + 8 * pi >= valid) {
        a[0][pi] = -3.0e38f; a[1][pi] = -3.0e38f;
        a[2][pi] = -3.0e38f; a[3][pi] = -3.0e38f;
      }

    // online softmax per mi (row-max over pi in-lane, pg via shuffles)
    float w[4][4];
#pragma unroll
    for (int mi = 0; mi < 4; ++mi) {
      float tmax = fmaxf(fmaxf(a[mi][0], a[mi][1]), fmaxf(a[mi][2], a[mi][3]));
      tmax = fmaxf(tmax, __shfl_xor(tmax, 8));
      tmax = fmaxf(tmax, __shfl_xor(tmax, 16));
      tmax = fmaxf(tmax, __shfl_xor(tmax, 32));
      const float mnew = fmaxf(mrun[mi], tmax);
      const float fc = __expf(mrun[mi] - mnew);
      mrun[mi] = mnew;
      float rs = 0.f;
#pragma unroll
      for (int pi = 0; pi < 4; ++pi) {
        w[mi][pi] = __expf(a[mi][pi] - mnew);
        rs += w[mi][pi];
      }
      rs += __shfl_xor(rs, 8);
      rs += __shfl_xor(rs, 16);
      rs += __shfl_xor(rs, 32);
      lrun[mi] = lrun[mi] * fc + rs;
      o[mi].x *= fc;
      o[mi].y *= fc;
    }

    // publish weights to the wave-private strip: lane (pg, dq<4) owns row
    // p = pg + 8*dq; select w[.][dq] via static-index ternaries (no scratch).
    if (dq < 4) {
      const int p = pg + 8 * dq;
      const float s0 = (dq == 0) ? w[0][0] : (dq == 1) ? w[0][1] : (dq == 2) ? w[0][2] : w[0][3];
      const float s1 = (dq == 0) ? w[1][0] : (dq == 1) ? w[1][1] : (dq == 2) ? w[1][2] : w[1][3];
      const float s2 = (dq == 0) ? w[2][0] : (dq == 1) ? w[2][1] : (dq == 2) ? w[2][2] : w[2][3];
      const float s3 = (dq == 0) ? w[3][0] : (dq == 1) ? w[3][1] : (dq == 2) ? w[3][2] : w[3][3];
      *reinterpret_cast<float2*>(&wx[wave][0][p][0]) = make_float2(s0, s1);
      *reinterpret_cast<float2*>(&wx[wave][1][p][0]) = make_float2(s2, s3);
    }
    // wave-internal LDS ordering: in-order per wave; compiler inserts lgkmcnt.

    // ---- PV: o[mi] (d = dl, dl+1) over the 32 rows, V streamed per row ----
#pragma unroll
    for (int p8 = 0; p8 < 4; ++p8) {
      float2 vv[8];
#pragma unroll
      for (int j = 0; j < 8; ++j) {
        int gp = sub * 32 + p8 * 8 + j; gp = (gp < valid) ? gp : (valid - 1);
        vv[j] = *reinterpret_cast<const float2*>(Vsrc + (size_t)gp * D_ + dl);
      }
#pragma unroll
      for (int j = 0; j < 8; ++j) {
        const float2 wa = *reinterpret_cast<const float2*>(&wx[wave][0][p8 * 8 + j][0]);
        const float2 wb = *reinterpret_cast<const float2*>(&wx[wave][1][p8 * 8 + j][0]);
        o[0].x = fmaf(wa.x, vv[j].x, o[0].x); o[0].y = fmaf(wa.x, vv[j].y, o[0].y);
        o[1].x = fmaf(wa.y, vv[j].x, o[1].x); o[1].y = fmaf(wa.y, vv[j].y, o[1].y);
        o[2].x = fmaf(wb.x, vv[j].x, o[2].x); o[2].y = fmaf(wb.x, vv[j].y, o[2].y);
        o[3].x = fmaf(wb.y, vv[j].x, o[3].x); o[3].y = fmaf(wb.y, vv[j].y, o[3].y);
      }
    }
  }

  // ---- write partials: wave owns rows m0..m0+3 fully ----
  const size_t base = (size_t)((h * NCH1 + c) * M_) * D_;
#pragma unroll
  for (int mi = 0; mi < 4; ++mi)
    *reinterpret_cast<float2*>(opart + base + (size_t)(m0 + mi) * D_ + dl) = o[mi];
  if (lane == 0) {
    const size_t mb = ((size_t)(h * NCH1 + c) * M_ + m0) * 2;
    ml[mb + 0] = mrun[0]; ml[mb + 1] = lrun[0];
    ml[mb + 2] = mrun[1]; ml[mb + 3] = lrun[1];
    ml[mb + 4] = mrun[2]; ml[mb + 5] = lrun[2];
    ml[mb + 6] = mrun[3]; ml[mb + 7] = lrun[3];
  }
}

// ---------------------------------------------------------------------------
// Kernel 4: combine 65 chunk partials per (h, m). grid (M_, H_), block 128.
// 4-way split accumulators for load ILP. (unchanged)
// ---------------------------------------------------------------------------
__global__ __launch_bounds__(128) void k_comb(const float* __restrict__ opart,
                                              const float* __restrict__ ml,
                                              float* __restrict__ out) {
  const int m = blockIdx.x, h = blockIdx.y, t = threadIdx.x;
  __shared__ float Ms[NCH1], Ls[NCH1];
  if (t < NCH1) {
    Ms[t] = ml[((size_t)(h * NCH1 + t) * M_ + m) * 2 + 0];
    Ls[t] = ml[((size_t)(h * NCH1 + t) * M_ + m) * 2 + 1];
  }
  __syncthreads();
  float gM = -3.0e38f;
#pragma unroll
  for (int c2 = 0; c2 < NCH1; ++c2) gM = fmaxf(gM, Ms[c2]);

  const float* __restrict__ ob = opart + (size_t)h * NCH1 * M_ * D_ + (size_t)m * D_ + t;
  float T = 0.f, o0 = 0.f, o1 = 0.f, o2 = 0.f, o3 = 0.f;
#pragma unroll 4
  for (int c2 = 0; c2 < NCH1 - 1; c2 += 4) {
    const float f0 = __expf(Ms[c2 + 0] - gM);
    const float f1 = __expf(Ms[c2 + 1] - gM);
    const float f2 = __expf(Ms[c2 + 2] - gM);
    const float f3 = __expf(Ms[c2 + 3] - gM);
    T = fmaf(Ls[c2 + 0], f0, T); T = fmaf(Ls[c2 + 1], f1, T);
    T = fmaf(Ls[c2 + 2], f2, T); T = fmaf(Ls[c2 + 3], f3, T);
    o0 = fmaf(ob[(size_t)(c2 + 0) * M_ * D_], f0, o0);
    o1 = fmaf(ob[(size_t)(c2 + 1) * M_ * D_], f1, o1);
    o2 = fmaf(ob[(size_t)(c2 + 2) * M_ * D_], f2, o2);
    o3 = fmaf(ob[(size_t)(c2 + 3) * M_ * D_], f3, o3);
  }
  {
    const int c2 = NCH1 - 1;
    const float f = __expf(Ms[c2] - gM);
    T = fmaf(Ls[c2], f, T);
    o0 = fmaf(ob[(size_t)c2 * M_ * D_], f, o0);
  }
  out[(size_t)m * N_ + h * D_ + t] = (o0 + o1 + o2 + o3) / T;
}

// ---------------------------------------------------------------------------
extern "C" void kernel_launch(void* const* d_in, const int* in_sizes, int n_in,
                              void* d_out, int out_size, void* d_ws, size_t ws_size,
                              hipStream_t stream) {
  const float* X  = (const float*)d_in[0];
  const float* Wq = (const float*)d_in[1];
  const float* Wk = (const float*)d_in[2];
  const float* Wv = (const float*)d_in[3];
  const float* cK = (const float*)d_in[4];
  const float* cV = (const float*)d_in[5];
  float* ws    = (float*)d_ws;
  float* qkv   = ws;
  float* part  = ws + PART_OFF;
  float* opart = ws + OPART_OFF;
  float* mlbuf = ws + ML_OFF;
  float* out   = (float*)d_out;

  hipLaunchKernelGGL(k_proj,   dim3(NCB, NIC, 3), dim3(256), 0, stream, X, Wq, Wk, Wv, part);
  hipLaunchKernelGGL(k_reduce, dim3(16, M_, 3),   dim3(256), 0, stream, part, qkv);
  hipLaunchKernelGGL(k_attn,   dim3(NCH1, H_),    dim3(256), 0, stream, cK, cV, qkv, opart, mlbuf);
  hipLaunchKernelGGL(k_comb,   dim3(M_, H_),      dim3(128), 0, stream, opart, mlbuf, out);
}

// Round 7
// 134.613 us; speedup vs baseline: 1.8103x; 1.1851x over previous
//
#include <hip/hip_runtime.h>
#include <math.h>

// Problem constants
#define M_ 16
#define N_ 4096
#define D_ 128
#define P_ 8192
#define H_ 32

// Projection tiling
#define NIC 32
#define ICH (N_/NIC)
#define NCB 16            // 256-column blocks, 1 col/thread

// Attention chunking
#define CHUNK 128
#define NCH (P_/CHUNK)    // 64 cache chunks
#define NCH1 (NCH+1)      // +1 for the 16 appended rows

// Workspace layout (float offsets)
#define QKV_SZ    (3*H_*M_*D_)
#define PART_OFF  (QKV_SZ)
#define OPART_OFF (QKV_SZ)
#define OPART_SZ  (H_*NCH1*M_*D_)
#define ML_OFF    (OPART_OFF + OPART_SZ)

// ---------------------------------------------------------------------------
// Kernel 1: partial QKV projection. grid (NCB, NIC, 3), block 256.
// W is single-use: NON-TEMPORAL loads so the 201MB W-stream does not evict
// the 268MB K/V working set from Infinity Cache between k_attn passes.
// part is write-once/read-once: nt store here, nt load in k_reduce.
// ---------------------------------------------------------------------------
__global__ __launch_bounds__(256) void k_proj(const float* __restrict__ X,
                                              const float* __restrict__ Wq,
                                              const float* __restrict__ Wk,
                                              const float* __restrict__ Wv,
                                              float* __restrict__ part) {
  const int mat = blockIdx.z;
  const float* __restrict__ W = (mat == 0) ? Wq : ((mat == 1) ? Wk : Wv);
  const int cb = blockIdx.x, ic = blockIdx.y;
  const int t = threadIdx.x;
  const int j0 = cb * 256 + t;
  const int i0 = ic * ICH;

  __shared__ __align__(16) float XT[ICH][20];

  {
    const int i_l = t & 127, mh = t >> 7;
#pragma unroll
    for (int r = 0; r < 8; ++r)
      XT[i_l][mh * 8 + r] = X[(size_t)(mh * 8 + r) * N_ + i0 + i_l];
  }
  __syncthreads();

  float acc[16];
#pragma unroll
  for (int m = 0; m < 16; ++m) acc[m] = 0.f;

#pragma unroll 8
  for (int i = 0; i < ICH; ++i) {
    const float wv = __builtin_nontemporal_load(W + (size_t)(i0 + i) * N_ + j0);
    float xr[16];
    {
      float4 xv;
      xv = *reinterpret_cast<const float4*>(&XT[i][0]);
      xr[0] = xv.x; xr[1] = xv.y; xr[2] = xv.z; xr[3] = xv.w;
      xv = *reinterpret_cast<const float4*>(&XT[i][4]);
      xr[4] = xv.x; xr[5] = xv.y; xr[6] = xv.z; xr[7] = xv.w;
      xv = *reinterpret_cast<const float4*>(&XT[i][8]);
      xr[8] = xv.x; xr[9] = xv.y; xr[10] = xv.z; xr[11] = xv.w;
      xv = *reinterpret_cast<const float4*>(&XT[i][12]);
      xr[12] = xv.x; xr[13] = xv.y; xr[14] = xv.z; xr[15] = xv.w;
    }
#pragma unroll
    for (int m = 0; m < 16; ++m) acc[m] = fmaf(xr[m], wv, acc[m]);
  }

#pragma unroll
  for (int m = 0; m < 16; ++m)
    __builtin_nontemporal_store(acc[m], part + (size_t)((mat * NIC + ic) * M_ + m) * N_ + j0);
}

// ---------------------------------------------------------------------------
// Kernel 2: reduce partials, RMS-norm q/k, relayout. nt loads of part.
// ---------------------------------------------------------------------------
__global__ __launch_bounds__(256) void k_reduce(const float* __restrict__ part,
                                                float* __restrict__ qkv) {
  const int mat = blockIdx.z, m = blockIdx.y, nc = blockIdx.x;
  const int t = threadIdx.x;
  const int n = nc * 256 + t;

  float s = 0.f;
#pragma unroll
  for (int ic = 0; ic < NIC; ++ic)
    s += __builtin_nontemporal_load(part + (size_t)((mat * NIC + ic) * M_ + m) * N_ + n);

  float ss = s * s;
#pragma unroll
  for (int off = 1; off < 64; off <<= 1) ss += __shfl_xor(ss, off);
  __shared__ float wsum[4];
  const int wave = t >> 6, lane = t & 63;
  if (lane == 0) wsum[wave] = ss;
  __syncthreads();
  const int half = t >> 7;
  const float tot = wsum[half * 2] + wsum[half * 2 + 1];
  const float scale = (mat < 2) ? rsqrtf(tot * (1.0f / 128.0f)) : 1.0f;

  const int h = n >> 7, d = n & 127;
  qkv[(size_t)((mat * H_ + h) * M_ + m) * D_ + d] = s * scale;
}

// ---------------------------------------------------------------------------
// Kernel 3: barrier-free streaming attention with guaranteed load batches.
// grid (NCH1, H_), block 256 = 4 independent waves; wave owns m0=4w..4w+3.
// 16-row subtiles; per subtile the schedule keeps 8-16 loads outstanding in
// EVERY compute phase:
//   issue vvA(8) -> scores on kk -> reload kk(s+1)(8) -> issue vvB(8)
//   -> shuffle-reduce/softmax/exchange -> PV-A(vvA) -> PV-B(vvB)
// No masking needed: valid is always a multiple of 16. No barriers in loop.
// VGPR budget ~120 (kk 32 + vvA/B 32 + qq 16 + acc/etc) to stay in the
// <=128 occupancy band (r5/r6 showed 64-step granularity).
// ---------------------------------------------------------------------------
__global__ __launch_bounds__(256, 2) void k_attn(const float* __restrict__ cacheK,
                                                 const float* __restrict__ cacheV,
                                                 const float* __restrict__ qkv,
                                                 float* __restrict__ opart,
                                                 float* __restrict__ ml) {
  const int c = blockIdx.x, h = blockIdx.y;
  const int t = threadIdx.x;
  const int wave = t >> 6, lane = t & 63;
  const int valid = (c < NCH) ? CHUNK : M_;
  const int nsub = (c < NCH) ? (CHUNK / 16) : 1;  // 8 subtiles, or 1 (tail)
  const float* __restrict__ Ksrc = (c < NCH)
      ? (cacheK + ((size_t)h * P_ + (size_t)c * CHUNK) * D_)
      : (qkv + (size_t)((1 * H_ + h) * M_) * D_);
  const float* __restrict__ Vsrc = (c < NCH)
      ? (cacheV + ((size_t)h * P_ + (size_t)c * CHUNK) * D_)
      : (qkv + (size_t)((2 * H_ + h) * M_) * D_);

  __shared__ __align__(16) float qs[M_ * D_];   // 8 KB, broadcast reads only
  __shared__ float wx[4][2][16][2];             // 1 KB wave-private weight strips

  // stage q (one barrier, the only one in the kernel)
  {
    const float4* src = reinterpret_cast<const float4*>(qkv + (size_t)(h * M_) * D_);
    float4* dst = reinterpret_cast<float4*>(qs);
    dst[t] = src[t];
    dst[t + 256] = src[t + 256];
  }
  __syncthreads();

  const int pg = lane >> 3, dq = lane & 7;  // scores: 8 rows x 8 d-groups
  const int m0 = wave * 4;
  const int dl = lane * 2;                  // PV: d-pair per lane

  float mrun[4] = {-3.0e38f, -3.0e38f, -3.0e38f, -3.0e38f};
  float lrun[4] = {0.f, 0.f, 0.f, 0.f};
  float2 o[4];
#pragma unroll
  for (int mi = 0; mi < 4; ++mi) o[mi] = make_float2(0.f, 0.f);

  // K batch: kk[pi*4+dd] = K[s*16 + pg + 8*pi][dd*32 + dq*4 ..+4)
  float4 kk[8];
#pragma unroll
  for (int pi = 0; pi < 2; ++pi)
#pragma unroll
    for (int dd = 0; dd < 4; ++dd)
      kk[pi * 4 + dd] = *reinterpret_cast<const float4*>(
          Ksrc + (size_t)(pg + 8 * pi) * D_ + dd * 32 + dq * 4);

#pragma unroll 1
  for (int s = 0; s < nsub; ++s) {
    // ---- issue vvA: rows s*16+0..7 (outstanding through scores) ----
    float2 vvA[8];
#pragma unroll
    for (int j = 0; j < 8; ++j)
      vvA[j] = *reinterpret_cast<const float2*>(Vsrc + (size_t)(s * 16 + j) * D_ + dl);

    // ---- scores: a[mi][pi] = q[m0+mi] . K[row] ----
    float a[4][2];
#pragma unroll
    for (int mi = 0; mi < 4; ++mi) { a[mi][0] = 0.f; a[mi][1] = 0.f; }
#pragma unroll
    for (int dd = 0; dd < 4; ++dd) {
      float4 qq[4];
#pragma unroll
      for (int mi = 0; mi < 4; ++mi)
        qq[mi] = *reinterpret_cast<const float4*>(&qs[(m0 + mi) * D_ + dd * 32 + dq * 4]);
#pragma unroll
      for (int mi = 0; mi < 4; ++mi)
#pragma unroll
        for (int pi = 0; pi < 2; ++pi) {
          const float4 kv = kk[pi * 4 + dd];
          a[mi][pi] = fmaf(qq[mi].x, kv.x, a[mi][pi]);
          a[mi][pi] = fmaf(qq[mi].y, kv.y, a[mi][pi]);
          a[mi][pi] = fmaf(qq[mi].z, kv.z, a[mi][pi]);
          a[mi][pi] = fmaf(qq[mi].w, kv.w, a[mi][pi]);
        }
    }

    // ---- reload kk for subtile s+1 (outstanding through softmax+PV) ----
#pragma unroll
    for (int pi = 0; pi < 2; ++pi)
#pragma unroll
      for (int dd = 0; dd < 4; ++dd) {
        int gp = (s + 1) * 16 + pg + 8 * pi;
        gp = (gp < valid) ? gp : (valid - 1);  // phantom prefetch on last iter
        kk[pi * 4 + dd] = *reinterpret_cast<const float4*>(
            Ksrc + (size_t)gp * D_ + dd * 32 + dq * 4);
      }

    // ---- issue vvB: rows s*16+8..15 (outstanding through softmax+PV-A) ----
    float2 vvB[8];
#pragma unroll
    for (int j = 0; j < 8; ++j)
      vvB[j] = *reinterpret_cast<const float2*>(Vsrc + (size_t)(s * 16 + 8 + j) * D_ + dl);

    // ---- reduce d-split over dq lanes (bits 0..2) ----
#pragma unroll
    for (int off = 1; off < 8; off <<= 1)
#pragma unroll
      for (int mi = 0; mi < 4; ++mi) {
        a[mi][0] += __shfl_xor(a[mi][0], off);
        a[mi][1] += __shfl_xor(a[mi][1], off);
      }

    // ---- online softmax per mi ----
    float w[4][2];
#pragma unroll
    for (int mi = 0; mi < 4; ++mi) {
      float tmax = fmaxf(a[mi][0], a[mi][1]);
      tmax = fmaxf(tmax, __shfl_xor(tmax, 8));
      tmax = fmaxf(tmax, __shfl_xor(tmax, 16));
      tmax = fmaxf(tmax, __shfl_xor(tmax, 32));
      const float mnew = fmaxf(mrun[mi], tmax);
      const float fc = __expf(mrun[mi] - mnew);
      mrun[mi] = mnew;
      w[mi][0] = __expf(a[mi][0] - mnew);
      w[mi][1] = __expf(a[mi][1] - mnew);
      float rs = w[mi][0] + w[mi][1];
      rs += __shfl_xor(rs, 8);
      rs += __shfl_xor(rs, 16);
      rs += __shfl_xor(rs, 32);
      lrun[mi] = lrun[mi] * fc + rs;
      o[mi].x *= fc;
      o[mi].y *= fc;
    }

    // ---- publish weights: lane (pg, dq<2) owns row p = pg + 8*dq ----
    if (dq < 2) {
      const int p = pg + 8 * dq;
      const float s0 = (dq == 0) ? w[0][0] : w[0][1];
      const float s1 = (dq == 0) ? w[1][0] : w[1][1];
      const float s2 = (dq == 0) ? w[2][0] : w[2][1];
      const float s3 = (dq == 0) ? w[3][0] : w[3][1];
      *reinterpret_cast<float2*>(&wx[wave][0][p][0]) = make_float2(s0, s1);
      *reinterpret_cast<float2*>(&wx[wave][1][p][0]) = make_float2(s2, s3);
    }
    // wave-internal LDS ordering: per-wave program order; compiler inserts lgkmcnt.

    // ---- PV-A: rows 0..7 of the subtile ----
#pragma unroll
    for (int j = 0; j < 8; ++j) {
      const float2 wa = *reinterpret_cast<const float2*>(&wx[wave][0][j][0]);
      const float2 wb = *reinterpret_cast<const float2*>(&wx[wave][1][j][0]);
      o[0].x = fmaf(wa.x, vvA[j].x, o[0].x); o[0].y = fmaf(wa.x, vvA[j].y, o[0].y);
      o[1].x = fmaf(wa.y, vvA[j].x, o[1].x); o[1].y = fmaf(wa.y, vvA[j].y, o[1].y);
      o[2].x = fmaf(wb.x, vvA[j].x, o[2].x); o[2].y = fmaf(wb.x, vvA[j].y, o[2].y);
      o[3].x = fmaf(wb.y, vvA[j].x, o[3].x); o[3].y = fmaf(wb.y, vvA[j].y, o[3].y);
    }
    // ---- PV-B: rows 8..15 ----
#pragma unroll
    for (int j = 0; j < 8; ++j) {
      const float2 wa = *reinterpret_cast<const float2*>(&wx[wave][0][8 + j][0]);
      const float2 wb = *reinterpret_cast<const float2*>(&wx[wave][1][8 + j][0]);
      o[0].x = fmaf(wa.x, vvB[j].x, o[0].x); o[0].y = fmaf(wa.x, vvB[j].y, o[0].y);
      o[1].x = fmaf(wa.y, vvB[j].x, o[1].x); o[1].y = fmaf(wa.y, vvB[j].y, o[1].y);
      o[2].x = fmaf(wb.x, vvB[j].x, o[2].x); o[2].y = fmaf(wb.x, vvB[j].y, o[2].y);
      o[3].x = fmaf(wb.y, vvB[j].x, o[3].x); o[3].y = fmaf(wb.y, vvB[j].y, o[3].y);
    }
  }

  // ---- write partials: wave owns rows m0..m0+3 fully ----
  const size_t base = (size_t)((h * NCH1 + c) * M_) * D_;
#pragma unroll
  for (int mi = 0; mi < 4; ++mi)
    *reinterpret_cast<float2*>(opart + base + (size_t)(m0 + mi) * D_ + dl) = o[mi];
  if (lane == 0) {
    const size_t mb = ((size_t)(h * NCH1 + c) * M_ + m0) * 2;
    ml[mb + 0] = mrun[0]; ml[mb + 1] = lrun[0];
    ml[mb + 2] = mrun[1]; ml[mb + 3] = lrun[1];
    ml[mb + 4] = mrun[2]; ml[mb + 5] = lrun[2];
    ml[mb + 6] = mrun[3]; ml[mb + 7] = lrun[3];
  }
}

// ---------------------------------------------------------------------------
// Kernel 4: combine 65 chunk partials per (h, m). grid (M_, H_), block 128.
// ---------------------------------------------------------------------------
__global__ __launch_bounds__(128) void k_comb(const float* __restrict__ opart,
                                              const float* __restrict__ ml,
                                              float* __restrict__ out) {
  const int m = blockIdx.x, h = blockIdx.y, t = threadIdx.x;
  __shared__ float Ms[NCH1], Ls[NCH1];
  if (t < NCH1) {
    Ms[t] = ml[((size_t)(h * NCH1 + t) * M_ + m) * 2 + 0];
    Ls[t] = ml[((size_t)(h * NCH1 + t) * M_ + m) * 2 + 1];
  }
  __syncthreads();
  float gM = -3.0e38f;
#pragma unroll
  for (int c2 = 0; c2 < NCH1; ++c2) gM = fmaxf(gM, Ms[c2]);

  const float* __restrict__ ob = opart + (size_t)h * NCH1 * M_ * D_ + (size_t)m * D_ + t;
  float T = 0.f, o0 = 0.f, o1 = 0.f, o2 = 0.f, o3 = 0.f;
#pragma unroll 4
  for (int c2 = 0; c2 < NCH1 - 1; c2 += 4) {
    const float f0 = __expf(Ms[c2 + 0] - gM);
    const float f1 = __expf(Ms[c2 + 1] - gM);
    const float f2 = __expf(Ms[c2 + 2] - gM);
    const float f3 = __expf(Ms[c2 + 3] - gM);
    T = fmaf(Ls[c2 + 0], f0, T); T = fmaf(Ls[c2 + 1], f1, T);
    T = fmaf(Ls[c2 + 2], f2, T); T = fmaf(Ls[c2 + 3], f3, T);
    o0 = fmaf(ob[(size_t)(c2 + 0) * M_ * D_], f0, o0);
    o1 = fmaf(ob[(size_t)(c2 + 1) * M_ * D_], f1, o1);
    o2 = fmaf(ob[(size_t)(c2 + 2) * M_ * D_], f2, o2);
    o3 = fmaf(ob[(size_t)(c2 + 3) * M_ * D_], f3, o3);
  }
  {
    const int c2 = NCH1 - 1;
    const float f = __expf(Ms[c2] - gM);
    T = fmaf(Ls[c2], f, T);
    o0 = fmaf(ob[(size_t)c2 * M_ * D_], f, o0);
  }
  out[(size_t)m * N_ + h * D_ + t] = (o0 + o1 + o2 + o3) / T;
}

// ---------------------------------------------------------------------------
extern "C" void kernel_launch(void* const* d_in, const int* in_sizes, int n_in,
                              void* d_out, int out_size, void* d_ws, size_t ws_size,
                              hipStream_t stream) {
  const float* X  = (const float*)d_in[0];
  const float* Wq = (const float*)d_in[1];
  const float* Wk = (const float*)d_in[2];
  const float* Wv = (const float*)d_in[3];
  const float* cK = (const float*)d_in[4];
  const float* cV = (const float*)d_in[5];
  float* ws    = (float*)d_ws;
  float* qkv   = ws;
  float* part  = ws + PART_OFF;
  float* opart = ws + OPART_OFF;
  float* mlbuf = ws + ML_OFF;
  float* out   = (float*)d_out;

  hipLaunchKernelGGL(k_proj,   dim3(NCB, NIC, 3), dim3(256), 0, stream, X, Wq, Wk, Wv, part);
  hipLaunchKernelGGL(k_reduce, dim3(16, M_, 3),   dim3(256), 0, stream, part, qkv);
  hipLaunchKernelGGL(k_attn,   dim3(NCH1, H_),    dim3(256), 0, stream, cK, cV, qkv, opart, mlbuf);
  hipLaunchKernelGGL(k_comb,   dim3(M_, H_),      dim3(128), 0, stream, opart, mlbuf, out);
}